// Round 9
// baseline (53.036 us; speedup 1.0000x reference)
//
#include <hip/hip_runtime.h>
#include <stdint.h>

typedef unsigned short u16;
typedef __attribute__((ext_vector_type(4))) float f32x4;
typedef __attribute__((ext_vector_type(8))) __bf16 bf16x8;

// ---- Cayley table for Cl(3,0), basis order [1,e1,e2,e3,e12,e13,e23,e123] ----
struct Cay { int idx[8][8]; float sgn[8][8]; };
constexpr int kOrder[8] = {0,1,2,4,3,5,6,7};
constexpr int ordpos(int m){ int r=-1; for(int i=0;i<8;i++) if(kOrder[i]==m) r=i; return r; }
constexpr Cay make_cay(){
  Cay c{};
  for(int ia=0; ia<8; ia++) for(int ib=0; ib<8; ib++){
    int a=kOrder[ia], b=kOrder[ib];
    int t=a>>1, tot=0;
    while(t){ int x=t&b; while(x){ tot+=x&1; x>>=1; } t>>=1; }
    c.idx[ia][ib]=ordpos(a^b);
    c.sgn[ia][ib]=(tot&1)?-1.0f:1.0f;
  }
  return c;
}
constexpr Cay CAY = make_cay();

// ---- squared-multivector GP at HALF SCALE for k!=0 (x2 folded into W2 grades 1..3) ----
struct GPTab { float dsgn[8]; int np; int pi[28]; int pj[28]; int pk[28]; float ps[28]; };
constexpr GPTab make_gptab(){
  GPTab t{};
  for (int i=0;i<8;i++) t.dsgn[i] = CAY.sgn[i][i];
  t.np = 0;
  for (int i=0;i<8;i++) for (int j=i+1;j<8;j++){
    float s = CAY.sgn[i][j] + CAY.sgn[j][i];      // in {-2,0,+2}
    if (s != 0.0f){ t.pi[t.np]=i; t.pj[t.np]=j; t.pk[t.np]=CAY.idx[i][j];
                    t.ps[t.np]=(s>0.f)?1.0f:-1.0f; t.np++; }
  }
  return t;
}
constexpr GPTab GPT = make_gptab();

__device__ __forceinline__ void gprod_half(const float* h, float* g){
  float g0 = h[0]*h[0];
  #pragma unroll
  for (int i=1;i<8;i++) g0 = fmaf(GPT.dsgn[i]>0.f ? h[i] : -h[i], h[i], g0);
  g[0] = g0;
  #pragma unroll
  for (int k=1;k<8;k++) g[k] = 0.f;
  #pragma unroll
  for (int t=0;t<GPT.np;t++)
    g[GPT.pk[t]] = fmaf(GPT.ps[t]>0.f ? h[GPT.pi[t]] : -h[GPT.pi[t]],
                        h[GPT.pj[t]], g[GPT.pk[t]]);
}

__device__ __forceinline__ u16 f2bf(float f){
  union { float f; uint32_t u; } v; v.f=f;
  uint32_t u=v.u;
  return (u16)((u + 0x7fffu + ((u>>16)&1u)) >> 16);   // RNE
}

__device__ __forceinline__ uint32_t cvtpk(float lo, float hi){
  uint32_t r;
  asm("v_cvt_pk_bf16_f32 %0, %1, %2" : "=v"(r) : "v"(lo), "v"(hi));
  return r;
}

// ---- weight repack ----
// w1p frag f=((g*2+ks)*8+ot): lane l, elem e -> W1[ot*16+(l&15)][ks*32+(l>>4)*8+e][g]
// w2p frag f=((g*4+ks)*4+ot): lane l, elem e -> W2[ot*16+(l&15)][ks*32+(l>>4)*8+e][g] * (g?2:1)
__global__ void gp_prepack(const float* __restrict__ W1, const float* __restrict__ W2,
                           u16* __restrict__ w1p, u16* __restrict__ w2p)
{
  int t = blockIdx.x*256 + threadIdx.x;   // 0..65535
  int e = t & 7, l = (t>>3)&63, f = t>>9;
  int lm = l & 15, lh = l >> 4;
  if (f < 64) {
    int g = f >> 4, ks = (f>>3)&1, ot = f&7;
    int o = ot*16 + lm, c = ks*32 + lh*8 + e;
    w1p[f*512 + l*8 + e] = f2bf(W1[(o*64 + c)*4 + g]);
  } else {
    int f2 = f - 64;
    int g = f2 >> 4, ks = (f2>>2)&3, ot = f2&3;
    int outc = ot*16 + lm, o = ks*32 + lh*8 + e;
    float sc = (g == 0) ? 1.0f : 2.0f;               // half-scale GP compensation
    w2p[f2*512 + l*8 + e] = f2bf(W2[(outc*128 + o)*4 + g] * sc);
  }
}

// ---- fully barrier-free fused kernel: one wave = one 16-pos tile ----
// Per-wave LDS: X tile [pos16][blade8][cin64] bf16 = 16 KB, swizzle byte ^= ((pos&7)<<4).
// G never hits LDS: s1 out (pos=lm, ch=lh*4+r) -> s2 A-frag (pos=lm, ch=lh*8+e) is a
// permutation within the 4-lane group {lm, lm+16, lm+32, lm+48}: cvt_pk + ds_bpermute.
__global__ __launch_bounds__(256,2) void gp_fused(
    const float* __restrict__ x, const u16* __restrict__ w1p,
    const float* __restrict__ b1, const u16* __restrict__ w2p,
    const float* __restrict__ b2, const float* __restrict__ avec,
    float* __restrict__ out)
{
  __shared__ __align__(16) char SH[65536];

  const int tid = threadIdx.x;
  const int w  = tid >> 6;
  const int l  = tid & 63;
  const int lm = l & 15;
  const int lh = l >> 4;
  char* XSH = SH + (w << 14);                 // private 16 KB per wave
  const size_t tile = (size_t)blockIdx.x*4 + w;   // 2048 tiles, one per wave

  constexpr int BSTART[4] = {0,1,4,7};
  constexpr int BCNT[4]   = {1,3,3,1};

  const uint4*  w1f = reinterpret_cast<const uint4*>(w1p);
  const uint4*  w2f = reinterpret_cast<const uint4*>(w2p);
  const float4* b1f = reinterpret_cast<const float4*>(b1);

  // ---- stage this wave's X tile (no barrier; intra-wave lgkmcnt only) ----
  {
    const float4* xt = reinterpret_cast<const float4*>(x) + tile*2048;
    #pragma unroll
    for (int it=0; it<8; ++it){
      const int p  = it*2 + (l>>5);           // pos 0..15
      const int cp = l & 31;                  // cin pair
      const float4* src = xt + p*128 + cp*4;
      float4 v0=src[0], v1=src[1], v2=src[2], v3=src[3];
      uint32_t pk[8];
      pk[0]=cvtpk(v0.x,v2.x); pk[1]=cvtpk(v0.y,v2.y); pk[2]=cvtpk(v0.z,v2.z); pk[3]=cvtpk(v0.w,v2.w);
      pk[4]=cvtpk(v1.x,v3.x); pk[5]=cvtpk(v1.y,v3.y); pk[6]=cvtpk(v1.z,v3.z); pk[7]=cvtpk(v1.w,v3.w);
      const int xo = (p & 7) << 4;
      #pragma unroll
      for (int b=0;b<8;b++)
        *reinterpret_cast<uint32_t*>(XSH + ((((p*8+b)<<7) + (cp<<2)) ^ xo)) = pk[b];
    }
  }

  const int xk = (lm & 7) << 4;
  // bpermute source addresses (bytes): src lane = lm + 16*(2*(lh&1) + (j>>1))
  const int pa_addr0 = (lm + ((lh & 1) << 5)) << 2;
  const int pa_addr1 = pa_addr0 + 64;
  const bool selA = (lh < 2);

  // persistent accumulator: all 4 oc-tiles x 8 blades
  f32x4 acc2[4][8];
  #pragma unroll
  for (int ot=0; ot<4; ++ot)
    #pragma unroll
    for (int b=0; b<8; ++b) acc2[ot][b] = (f32x4){0.f,0.f,0.f,0.f};

  #pragma unroll 1
  for (int s=0; s<4; ++s){                    // ch-slice: ch 32s..32s+31 (cht 2s, 2s+1)
    uint32_t packA[16], packB[16];            // [blade*2 + rpair], bf16-pairs of G

    #pragma unroll
    for (int half=0; half<2; ++half){
      const int cht = 2*s + half;
      // stage-1 weight frags for this cht (8x uint4, transient)
      uint4 wf[8];
      #pragma unroll
      for (int i=0;i<8;++i) wf[i] = w1f[(i*8 + cht)*64 + l];

      f32x4 acc1[8];
      #pragma unroll
      for (int b=0;b<8;++b) acc1[b] = (f32x4){0.f,0.f,0.f,0.f};

      #pragma unroll
      for (int g4=0; g4<4; ++g4){
        #pragma unroll
        for (int ks=0; ks<2; ++ks){
          bf16x8 wv = __builtin_bit_cast(bf16x8, wf[g4*2+ks]);
          #pragma unroll
          for (int bi=0; bi<3; ++bi){
            if (bi >= BCNT[g4]) break;
            const int blade = BSTART[g4] + bi;
            bf16x8 xv = *reinterpret_cast<const bf16x8*>(
                XSH + ((((lm*8+blade)<<7) + ((ks*32+lh*8)<<1)) ^ xk));
            acc1[blade] = __builtin_amdgcn_mfma_f32_16x16x32_bf16(wv, xv, acc1[blade], 0,0,0);
          }
        }
      }

      // GP (half-scale) for the 4 elements (pos=lm, ch=cht*16+lh*4+r)
      const float4 bb4 = b1f[cht*4 + lh];
      const float bb[4] = {bb4.x, bb4.y, bb4.z, bb4.w};
      float gg[4][8];
      #pragma unroll
      for (int r=0; r<4; ++r){
        float h[8];
        #pragma unroll
        for (int b=0;b<8;b++) h[b] = acc1[b][r];
        h[0] += bb[r];
        gprod_half(h, gg[r]);
      }
      uint32_t* dst = half ? packB : packA;
      #pragma unroll
      for (int b=0;b<8;b++){
        dst[b*2+0] = cvtpk(gg[0][b], gg[1][b]);   // ch offsets 4lh, 4lh+1
        dst[b*2+1] = cvtpk(gg[2][b], gg[3][b]);   // ch offsets 4lh+2, 4lh+3
      }
    }

    // ---- stage 2 for this slice: PA via 4-lane bpermute, 4 ot MFMAs per blade ----
    #pragma unroll
    for (int g4=0; g4<4; ++g4){
      uint4 wq0 = w2f[((g4*4+s)*4 + 0)*64 + l];
      uint4 wq1 = w2f[((g4*4+s)*4 + 1)*64 + l];
      uint4 wq2 = w2f[((g4*4+s)*4 + 2)*64 + l];
      uint4 wq3 = w2f[((g4*4+s)*4 + 3)*64 + l];
      #pragma unroll
      for (int bi=0; bi<3; ++bi){
        if (bi >= BCNT[g4]) break;
        const int b = BSTART[g4] + bi;
        uint32_t tA, tB;
        uint4 pu;
        tA = __builtin_amdgcn_ds_bpermute(pa_addr0, packA[b*2+0]);
        tB = __builtin_amdgcn_ds_bpermute(pa_addr0, packB[b*2+0]);
        pu.x = selA ? tA : tB;
        tA = __builtin_amdgcn_ds_bpermute(pa_addr0, packA[b*2+1]);
        tB = __builtin_amdgcn_ds_bpermute(pa_addr0, packB[b*2+1]);
        pu.y = selA ? tA : tB;
        tA = __builtin_amdgcn_ds_bpermute(pa_addr1, packA[b*2+0]);
        tB = __builtin_amdgcn_ds_bpermute(pa_addr1, packB[b*2+0]);
        pu.z = selA ? tA : tB;
        tA = __builtin_amdgcn_ds_bpermute(pa_addr1, packA[b*2+1]);
        tB = __builtin_amdgcn_ds_bpermute(pa_addr1, packB[b*2+1]);
        pu.w = selA ? tA : tB;
        bf16x8 pav = __builtin_bit_cast(bf16x8, pu);
        acc2[0][b] = __builtin_amdgcn_mfma_f32_16x16x32_bf16(pav, __builtin_bit_cast(bf16x8, wq0), acc2[0][b], 0,0,0);
        acc2[1][b] = __builtin_amdgcn_mfma_f32_16x16x32_bf16(pav, __builtin_bit_cast(bf16x8, wq1), acc2[1][b], 0,0,0);
        acc2[2][b] = __builtin_amdgcn_mfma_f32_16x16x32_bf16(pav, __builtin_bit_cast(bf16x8, wq2), acc2[2][b], 0,0,0);
        acc2[3][b] = __builtin_amdgcn_mfma_f32_16x16x32_bf16(pav, __builtin_bit_cast(bf16x8, wq3), acc2[3][b], 0,0,0);
      }
    }
  }

  // ---- epilogue (barrier-free): bias, norms, mean over 64 oc, scale, store ----
  float b2v[4], av[4];
  #pragma unroll
  for (int ot=0; ot<4; ++ot){ b2v[ot] = b2[ot*16+lm]; av[ot] = avec[ot*16+lm]; }
  #pragma unroll
  for (int ot=0; ot<4; ++ot)
    #pragma unroll
    for (int r=0; r<4; ++r) acc2[ot][0][r] += b2v[ot];

  float nrm[4];                                // per r (pos = lh*4+r), summed over lane's 4 oc
  #pragma unroll
  for (int r=0; r<4; ++r){
    float sum = 0.f;
    #pragma unroll
    for (int ot=0; ot<4; ++ot){
      float ss = 0.f;
      #pragma unroll
      for (int b=0; b<8; ++b) ss = fmaf(acc2[ot][b][r], acc2[ot][b][r], ss);
      sum += sqrtf(ss);
    }
    nrm[r] = sum;
  }
  #pragma unroll
  for (int r=0; r<4; ++r){                     // reduce over the 16 lm lanes
    float v = nrm[r];
    v += __shfl_xor(v, 1, 64);
    v += __shfl_xor(v, 2, 64);
    v += __shfl_xor(v, 4, 64);
    v += __shfl_xor(v, 8, 64);
    nrm[r] = v;                                // sum over all 64 oc for pos lh*4+r
  }

  #pragma unroll
  for (int r=0; r<4; ++r){
    const float denom = nrm[r]*(1.0f/64.0f) + 1e-6f;
    const float rde = __builtin_amdgcn_rcpf(denom);
    const size_t P = tile*16 + (size_t)(lh*4 + r);
    #pragma unroll
    for (int ot=0; ot<4; ++ot){
      const float sc = av[ot] * rde;
      float4 o0, o1;
      o0.x = acc2[ot][0][r]*sc; o0.y = acc2[ot][1][r]*sc;
      o0.z = acc2[ot][2][r]*sc; o0.w = acc2[ot][3][r]*sc;
      o1.x = acc2[ot][4][r]*sc; o1.y = acc2[ot][5][r]*sc;
      o1.z = acc2[ot][6][r]*sc; o1.w = acc2[ot][7][r]*sc;
      float4* op = reinterpret_cast<float4*>(out + (P*64 + (size_t)(ot*16+lm))*8);
      op[0] = o0; op[1] = o1;
    }
  }
}

extern "C" void kernel_launch(void* const* d_in, const int* in_sizes, int n_in,
                              void* d_out, int out_size, void* d_ws, size_t ws_size,
                              hipStream_t stream)
{
  const float* x  = (const float*)d_in[0];
  const float* W1 = (const float*)d_in[1];
  const float* b1 = (const float*)d_in[2];
  const float* W2 = (const float*)d_in[3];
  const float* b2 = (const float*)d_in[4];
  const float* a  = (const float*)d_in[5];
  float* out = (float*)d_out;

  u16* w1p = (u16*)d_ws;          // 64 KB
  u16* w2p = w1p + 32768;         // 64 KB

  gp_prepack<<<256, 256, 0, stream>>>(W1, W2, w1p, w2p);
  gp_fused<<<512, 256, 0, stream>>>(x, w1p, b1, w2p, b2, a, out);
}